// Round 5
// baseline (129.052 us; speedup 1.0000x reference)
//
#include <hip/hip_runtime.h>
#include <math.h>

#define DD 128
#define NSPLIT 32
#define JT 64
#define NBINS 512
#define SHIFT 10.0f
#define L2E_T 14.4269504089f   // 10 * log2(e)

typedef _Float16 f16x8 __attribute__((ext_vector_type(8)));
typedef _Float16 f16x2 __attribute__((ext_vector_type(2)));
typedef float f32x4 __attribute__((ext_vector_type(4)));

// ---- normalize rows -> f16, labels, histogram (no fn, no G) ----
__global__ __launch_bounds__(256)
void norm_kernel(const float* __restrict__ f, const int* __restrict__ labels,
                 _Float16* __restrict__ fh, int* __restrict__ labm,
                 int* __restrict__ hist, int M, int nrep)
{
    int gw = (blockIdx.x * 256 + threadIdx.x) >> 6;   // one wave per row
    int lane = threadIdx.x & 63;
    if (gw >= M) return;
    float2 v = *reinterpret_cast<const float2*>(&f[(size_t)gw * DD + lane * 2]);
    float ss = v.x * v.x + v.y * v.y;
    #pragma unroll
    for (int m = 1; m < 64; m <<= 1) ss += __shfl_xor(ss, m);
    float inv = 1.0f / fmaxf(sqrtf(ss), 1e-12f);
    f16x2 h; h[0] = (_Float16)(v.x * inv); h[1] = (_Float16)(v.y * inv);
    *reinterpret_cast<f16x2*>(&fh[(size_t)gw * DD + lane * 2]) = h;
    if (lane == 0) {
        int lb = labels[gw / nrep];
        labm[gw] = lb;
        if ((gw % nrep) == 0) atomicAdd(&hist[lb], nrep);  // one atomic per sample
    }
}

// ---- main: LDS-shared j-tiles, f16 MFMA, fused exp-sum + masked P-sum ----
// Block: 4 waves x 64 register-resident i-rows (bfr, 64 VGPR). j streams in
// 64-row LDS tiles (16KB x2, double-buffered), staged reg->LDS with XOR
// chunk swizzle (slot c^row&15 -> 2-way bank = free). Pipeline per iter:
// ds_write(tile t+1) ; gload(tile t+2) ; compute(t) ; lgkmcnt(0)+s_barrier.
// Raw barrier (NOT __syncthreads) so prefetch vmcnt survives the barrier.
// No diag handling here: final kernel subtracts the exact self-term.
__global__ __launch_bounds__(256, 3)
void supcon_main(const _Float16* __restrict__ fh, const int* __restrict__ labm,
                 float* __restrict__ Epart, float* __restrict__ Ppart,
                 int M, int jchunk)
{
    __shared__ _Float16 Ab0[JT * DD];
    __shared__ _Float16 Ab1[JT * DD];
    __shared__ int Lbuf[512];

    const int tid = threadIdx.x;
    const int lane = tid & 63;
    const int w = tid >> 6;
    const int ibase = blockIdx.x * 256 + w * 64;
    const int rowsel = lane & 15;
    const int grp = lane >> 4;
    const int ksel = grp * 8;
    const int jstart = blockIdx.y * jchunk;
    const int ntile = jchunk / JT;

    // register-resident Fi fragments: 4 subtiles x 4 K-steps = 64 VGPR
    f16x8 bfr[4][4];
    #pragma unroll
    for (int t = 0; t < 4; ++t)
        #pragma unroll
        for (int kk = 0; kk < 4; ++kk)
            bfr[t][kk] = *reinterpret_cast<const f16x8*>(
                &fh[(size_t)(ibase + t * 16 + rowsel) * DD + kk * 32 + ksel]);

    int li[4];
    #pragma unroll
    for (int t = 0; t < 4; ++t) li[t] = labm[ibase + t * 16 + rowsel];

    // j-chunk labels -> LDS (read later as int4 broadcast)
    for (int k = tid; k < jchunk; k += 256) Lbuf[k] = labm[jstart + k];

    // staging geometry: thread loads 4 x 16B chunks; chunk g -> (row, c)
    int srow[4], scx[4];
    #pragma unroll
    for (int p = 0; p < 4; ++p) {
        int g = p * 256 + tid;
        srow[p] = g >> 4;
        scx[p] = g & 15;
    }
    // read-side swizzled chunk offsets (in halves); row&15 == rowsel
    int rchunk[4];
    #pragma unroll
    for (int kk = 0; kk < 4; ++kk) rchunk[kk] = ((kk * 4 + grp) ^ rowsel) * 8;

    float esum[4] = {0.f, 0.f, 0.f, 0.f};
    float psum[4] = {0.f, 0.f, 0.f, 0.f};
    float4 R[4];

#define GLOAD(tt) { _Pragma("unroll") for (int p = 0; p < 4; ++p) \
    R[p] = *reinterpret_cast<const float4*>( \
        &fh[(size_t)(jstart + (tt) * JT + srow[p]) * DD + scx[p] * 8]); }

#define DSWRITE(B) { _Pragma("unroll") for (int p = 0; p < 4; ++p) \
    *reinterpret_cast<float4*>( \
        &B[(srow[p] * 16 + (scx[p] ^ (srow[p] & 15))) * 8]) = R[p]; }

#define BARRIER() { asm volatile("s_waitcnt lgkmcnt(0)" ::: "memory"); \
    __builtin_amdgcn_sched_barrier(0); \
    __builtin_amdgcn_s_barrier(); }

#define COMPUTE(B, tt) { \
    _Pragma("unroll") for (int s = 0; s < 4; ++s) { \
        f16x8 af[4]; \
        _Pragma("unroll") for (int kk = 0; kk < 4; ++kk) \
            af[kk] = *reinterpret_cast<const f16x8*>( \
                &B[(s * 16 + rowsel) * DD + rchunk[kk]]); \
        const int4 lj = *reinterpret_cast<const int4*>( \
            &Lbuf[(tt) * JT + s * 16 + grp * 4]); \
        _Pragma("unroll") for (int t = 0; t < 4; ++t) { \
            f32x4 acc = {0.f, 0.f, 0.f, 0.f}; \
            _Pragma("unroll") for (int kk = 0; kk < 4; ++kk) \
                acc = __builtin_amdgcn_mfma_f32_16x16x32_f16(af[kk], bfr[t][kk], acc, 0, 0, 0); \
            _Pragma("unroll") for (int r = 0; r < 4; ++r) { \
                float a = acc[r]; \
                int ljv = (r == 0) ? lj.x : (r == 1) ? lj.y : (r == 2) ? lj.z : lj.w; \
                esum[t] += exp2f(__builtin_fmaf(a, L2E_T, -L2E_T)); \
                psum[t] += (ljv == li[t]) ? a : 0.f; } } } }

    _Float16* bufA = Ab0;
    _Float16* bufB = Ab1;

    GLOAD(0); DSWRITE(bufA);
    if (ntile > 1) GLOAD(1);
    BARRIER();
    for (int tt = 0; tt < ntile; ++tt) {
        if (tt + 1 < ntile) DSWRITE(bufB);   // R holds tile tt+1
        if (tt + 2 < ntile) GLOAD(tt + 2);   // prefetch; hidden under compute
        COMPUTE(bufA, tt);
        BARRIER();
        _Float16* tmp = bufA; bufA = bufB; bufB = tmp;
    }
#undef GLOAD
#undef DSWRITE
#undef BARRIER
#undef COMPUTE

    // fold lane groups (bits 4,5 = different j rows of same i)
    #pragma unroll
    for (int t = 0; t < 4; ++t) {
        float e = esum[t], p = psum[t];
        e += __shfl_xor(e, 16); e += __shfl_xor(e, 32);
        p += __shfl_xor(p, 16); p += __shfl_xor(p, 32);
        if (lane < 16) {
            size_t o = (size_t)blockIdx.y * M + ibase + t * 16 + lane;
            Epart[o] = e;
            Ppart[o] = p;
        }
    }
}

// ---- per-row loss term (exact self-term subtraction) + global reduce ----
__global__ __launch_bounds__(256)
void final_fused(const _Float16* __restrict__ fh, const float* __restrict__ Epart,
                 const float* __restrict__ Ppart, const int* __restrict__ labm,
                 const int* __restrict__ hist, float* __restrict__ out, int M)
{
    __shared__ float red[4];
    int i = (blockIdx.x * 256 + threadIdx.x) >> 6;   // wave per row
    int lane = threadIdx.x & 63;
    f16x2 h = *reinterpret_cast<const f16x2*>(&fh[(size_t)i * DD + lane * 2]);
    float x0 = (float)h[0], x1 = (float)h[1];
    float aii = x0 * x0 + x1 * x1;                   // f16 self-dot in fp32
    #pragma unroll
    for (int m = 1; m < 64; m <<= 1) aii += __shfl_xor(aii, m);
    float ep = (lane < 32) ? Epart[(size_t)lane * M + i]
                           : Ppart[(size_t)(lane - 32) * M + i];
    #pragma unroll
    for (int m = 1; m < 32; m <<= 1) ep += __shfl_xor(ep, m);  // within 32-halves
    float P = __shfl(ep, 32);
    float term = 0.f;
    if (lane == 0) {
        int lb = labm[i];
        float cnt = (float)(hist[lb] - 1);
        float E = ep - exp2f(__builtin_fmaf(aii, L2E_T, -L2E_T)); // drop self exp
        float Pc = SHIFT * (P - aii);                              // drop self dot
        term = (SHIFT + logf(E)) - Pc / cnt;
    }
    int wv = threadIdx.x >> 6;
    if (lane == 0) red[wv] = term;
    __syncthreads();
    if (threadIdx.x == 0)
        atomicAdd(out, (red[0] + red[1] + red[2] + red[3]) / (float)M);
}

extern "C" void kernel_launch(void* const* d_in, const int* in_sizes, int n_in,
                              void* d_out, int out_size, void* d_ws, size_t ws_size,
                              hipStream_t stream)
{
    const float* feats = (const float*)d_in[0];
    const int* labels = (const int*)d_in[1];
    const int Bn = in_sizes[1];
    const int M = in_sizes[0] / DD;    // 8192
    const int nrep = M / Bn;           // 2

    char* ws = (char*)d_ws;
    _Float16* fh = (_Float16*)ws;
    size_t off = (size_t)M * DD * sizeof(_Float16);
    int* labm = (int*)(ws + off); off += (size_t)M * sizeof(int);
    int* hist = (int*)(ws + off); off += (size_t)NBINS * sizeof(int);
    off = (off + 255) & ~(size_t)255;
    float* Epart = (float*)(ws + off); off += (size_t)NSPLIT * M * sizeof(float);
    float* Ppart = (float*)(ws + off); off += (size_t)NSPLIT * M * sizeof(float);

    hipMemsetAsync(hist, 0, NBINS * sizeof(int), stream);
    hipMemsetAsync(d_out, 0, sizeof(float), stream);

    norm_kernel<<<M / 4, 256, 0, stream>>>(feats, labels, fh, labm, hist, M, nrep);

    const int jchunk = M / NSPLIT;     // 256 -> ntile = 4
    dim3 grid(M / 256, NSPLIT);        // 32 x 32 = 1024 blocks
    supcon_main<<<grid, 256, 0, stream>>>(fh, labm, Epart, Ppart, M, jchunk);

    final_fused<<<M / 4, 256, 0, stream>>>(fh, Epart, Ppart, labm, hist, (float*)d_out, M);
}

// Round 6
// 95.408 us; speedup vs baseline: 1.3526x; 1.3526x over previous
//
#include <hip/hip_runtime.h>
#include <math.h>

#define DD 128
#define NSPLIT 32
#define NBINS 512
#define SHIFT 10.0f
#define L2E_T 14.4269504089f   // 10 * log2(e)

typedef _Float16 f16x8 __attribute__((ext_vector_type(8)));
typedef _Float16 f16x2 __attribute__((ext_vector_type(2)));
typedef float f32x4 __attribute__((ext_vector_type(4)));

// ---- normalize rows -> f16, labels, histogram ----
__global__ __launch_bounds__(256)
void norm_kernel(const float* __restrict__ f, const int* __restrict__ labels,
                 _Float16* __restrict__ fh, int* __restrict__ labm,
                 int* __restrict__ hist, int M, int nrep)
{
    int gw = (blockIdx.x * 256 + threadIdx.x) >> 6;   // one wave per row
    int lane = threadIdx.x & 63;
    if (gw >= M) return;
    float2 v = *reinterpret_cast<const float2*>(&f[(size_t)gw * DD + lane * 2]);
    float ss = v.x * v.x + v.y * v.y;
    #pragma unroll
    for (int m = 1; m < 64; m <<= 1) ss += __shfl_xor(ss, m);
    float inv = 1.0f / fmaxf(sqrtf(ss), 1e-12f);
    f16x2 h; h[0] = (_Float16)(v.x * inv); h[1] = (_Float16)(v.y * inv);
    *reinterpret_cast<f16x2*>(&fh[(size_t)gw * DD + lane * 2]) = h;
    if (lane == 0) {
        int lb = labels[gw / nrep];
        labm[gw] = lb;
        if ((gw % nrep) == 0) atomicAdd(&hist[lb], nrep);  // one atomic per sample
    }
}

// ---- main: barrier-free f16 MFMA stream, fused exp-sum + masked P-sum ----
// 4 waves/block, no LDS, no barriers, no asm. Wave owns 64 i-rows register-
// resident (bfr[4][4] = 64 regs). j streams as 16-row subtiles loaded straight
// from L1/L2 (af = 16 regs); TLP (16 waves/CU, all desynchronized) hides the
// load latency. Register demand ~110 < 128 -> 4 waves/SIMD, no spill.
// S^T via mfma(A=Fj, B=Fi): i = lane&15 (lane-local), j = (lane>>4)*4 + r.
// Diagonal/self-pair included here; final kernel subtracts it exactly.
__global__ __launch_bounds__(256, 3)
void supcon_main(const _Float16* __restrict__ fh, const int* __restrict__ labm,
                 float* __restrict__ Epart, float* __restrict__ Ppart,
                 int M, int jchunk)
{
    const int lane = threadIdx.x & 63;
    const int w = threadIdx.x >> 6;
    const int ibase = blockIdx.x * 256 + w * 64;
    const int rowsel = lane & 15;
    const int grp = lane >> 4;
    const int ksel = grp * 8;      // f16 k-offset within a 32-wide K step

    // register-resident Fi fragments: 4 subtiles x 4 K-steps = 64 regs
    f16x8 bfr[4][4];
    #pragma unroll
    for (int t = 0; t < 4; ++t)
        #pragma unroll
        for (int kk = 0; kk < 4; ++kk)
            bfr[t][kk] = *reinterpret_cast<const f16x8*>(
                &fh[(size_t)(ibase + t * 16 + rowsel) * DD + kk * 32 + ksel]);

    int li[4];
    #pragma unroll
    for (int t = 0; t < 4; ++t) li[t] = labm[ibase + t * 16 + rowsel];

    float esum[4] = {0.f, 0.f, 0.f, 0.f};
    float psum[4] = {0.f, 0.f, 0.f, 0.f};

    const int j0 = blockIdx.y * jchunk;
    const _Float16* aptr = fh + (size_t)(j0 + rowsel) * DD + ksel;
    const int* lptr = labm + j0 + grp * 4;
    const int nsub = jchunk >> 4;      // 16-row j-subtiles

    for (int s = 0; s < nsub; ++s) {
        f16x8 af[4];
        #pragma unroll
        for (int kk = 0; kk < 4; ++kk)
            af[kk] = *reinterpret_cast<const f16x8*>(aptr + (size_t)s * 16 * DD + kk * 32);
        const int4 lj = *reinterpret_cast<const int4*>(lptr + s * 16);
        #pragma unroll
        for (int t = 0; t < 4; ++t) {
            f32x4 acc = {0.f, 0.f, 0.f, 0.f};
            #pragma unroll
            for (int kk = 0; kk < 4; ++kk)
                acc = __builtin_amdgcn_mfma_f32_16x16x32_f16(af[kk], bfr[t][kk], acc, 0, 0, 0);
            #pragma unroll
            for (int r = 0; r < 4; ++r) {
                float a = acc[r];
                int ljv = (r == 0) ? lj.x : (r == 1) ? lj.y : (r == 2) ? lj.z : lj.w;
                esum[t] += exp2f(__builtin_fmaf(a, L2E_T, -L2E_T));  // exp((a-1)*10)
                psum[t] += (ljv == li[t]) ? a : 0.f;
            }
        }
    }

    // fold lane groups (bits 4,5 = different j rows of the same i)
    #pragma unroll
    for (int t = 0; t < 4; ++t) {
        float e = esum[t], p = psum[t];
        e += __shfl_xor(e, 16); e += __shfl_xor(e, 32);
        p += __shfl_xor(p, 16); p += __shfl_xor(p, 32);
        if (lane < 16) {
            size_t o = (size_t)blockIdx.y * M + ibase + t * 16 + lane;
            Epart[o] = e;
            Ppart[o] = p;
        }
    }
}

// ---- per-row loss term (exact self-term subtraction) + global reduce ----
__global__ __launch_bounds__(256)
void final_fused(const _Float16* __restrict__ fh, const float* __restrict__ Epart,
                 const float* __restrict__ Ppart, const int* __restrict__ labm,
                 const int* __restrict__ hist, float* __restrict__ out, int M)
{
    __shared__ float red[4];
    int i = (blockIdx.x * 256 + threadIdx.x) >> 6;   // wave per row
    int lane = threadIdx.x & 63;
    f16x2 h = *reinterpret_cast<const f16x2*>(&fh[(size_t)i * DD + lane * 2]);
    float x0 = (float)h[0], x1 = (float)h[1];
    float aii = x0 * x0 + x1 * x1;                   // f16 self-dot in fp32
    #pragma unroll
    for (int m = 1; m < 64; m <<= 1) aii += __shfl_xor(aii, m);
    float ep = (lane < 32) ? Epart[(size_t)lane * M + i]
                           : Ppart[(size_t)(lane - 32) * M + i];
    #pragma unroll
    for (int m = 1; m < 32; m <<= 1) ep += __shfl_xor(ep, m);  // within 32-halves
    float P = __shfl(ep, 32);
    float term = 0.f;
    if (lane == 0) {
        int lb = labm[i];
        float cnt = (float)(hist[lb] - 1);
        float E = ep - exp2f(__builtin_fmaf(aii, L2E_T, -L2E_T)); // drop self exp
        float Pc = SHIFT * (P - aii);                              // drop self dot
        term = (SHIFT + logf(E)) - Pc / cnt;
    }
    int wv = threadIdx.x >> 6;
    if (lane == 0) red[wv] = term;
    __syncthreads();
    if (threadIdx.x == 0)
        atomicAdd(out, (red[0] + red[1] + red[2] + red[3]) / (float)M);
}

extern "C" void kernel_launch(void* const* d_in, const int* in_sizes, int n_in,
                              void* d_out, int out_size, void* d_ws, size_t ws_size,
                              hipStream_t stream)
{
    const float* feats = (const float*)d_in[0];
    const int* labels = (const int*)d_in[1];
    const int Bn = in_sizes[1];
    const int M = in_sizes[0] / DD;    // 8192
    const int nrep = M / Bn;           // 2

    char* ws = (char*)d_ws;
    _Float16* fh = (_Float16*)ws;
    size_t off = (size_t)M * DD * sizeof(_Float16);
    int* labm = (int*)(ws + off); off += (size_t)M * sizeof(int);
    int* hist = (int*)(ws + off); off += (size_t)NBINS * sizeof(int);
    off = (off + 255) & ~(size_t)255;
    float* Epart = (float*)(ws + off); off += (size_t)NSPLIT * M * sizeof(float);
    float* Ppart = (float*)(ws + off); off += (size_t)NSPLIT * M * sizeof(float);

    hipMemsetAsync(hist, 0, NBINS * sizeof(int), stream);
    hipMemsetAsync(d_out, 0, sizeof(float), stream);

    norm_kernel<<<M / 4, 256, 0, stream>>>(feats, labels, fh, labm, hist, M, nrep);

    const int jchunk = M / NSPLIT;     // 256 -> 16 subtiles per wave
    dim3 grid(M / 256, NSPLIT);        // 32 x 32 = 1024 blocks (4 per CU)
    supcon_main<<<grid, 256, 0, stream>>>(fh, labm, Epart, Ppart, M, jchunk);

    final_fused<<<M / 4, 256, 0, stream>>>(fh, Epart, Ppart, labm, hist, (float*)d_out, M);
}

// Round 7
// 85.200 us; speedup vs baseline: 1.5147x; 1.1198x over previous
//
#include <hip/hip_runtime.h>
#include <math.h>

#define DD 128
#define NSPLIT 16
#define NBINS 512
#define SHIFT 10.0f
#define L2E_T 14.4269504089f   // 10 * log2(e)

typedef _Float16 f16x8 __attribute__((ext_vector_type(8)));
typedef _Float16 f16x2 __attribute__((ext_vector_type(2)));
typedef float f32x4 __attribute__((ext_vector_type(4)));

// ---- normalize rows -> f16, labels, histogram ----
__global__ __launch_bounds__(256)
void norm_kernel(const float* __restrict__ f, const int* __restrict__ labels,
                 _Float16* __restrict__ fh, int* __restrict__ labm,
                 int* __restrict__ hist, int M, int nrep)
{
    int gw = (blockIdx.x * 256 + threadIdx.x) >> 6;   // one wave per row
    int lane = threadIdx.x & 63;
    if (gw >= M) return;
    float2 v = *reinterpret_cast<const float2*>(&f[(size_t)gw * DD + lane * 2]);
    float ss = v.x * v.x + v.y * v.y;
    #pragma unroll
    for (int m = 1; m < 64; m <<= 1) ss += __shfl_xor(ss, m);
    float inv = 1.0f / fmaxf(sqrtf(ss), 1e-12f);
    f16x2 h; h[0] = (_Float16)(v.x * inv); h[1] = (_Float16)(v.y * inv);
    *reinterpret_cast<f16x2*>(&fh[(size_t)gw * DD + lane * 2]) = h;
    if (lane == 0) {
        int lb = labels[gw / nrep];
        labm[gw] = lb;
        if ((gw % nrep) == 0) atomicAdd(&hist[lb], nrep);  // one atomic per sample
    }
}

// ---- main: barrier-free f16 MFMA stream, software-pipelined j-subtiles ----
// 4 waves/block, no LDS, no barriers. Wave owns 64 register-resident i-rows
// (bfr[4][4], AGPR-resident since they only feed MFMA). j streams as 16-row
// subtiles, 2x-unrolled ping-pong (af0/af1): per half-iteration the order is
// {16 MFMA on cur} -> {issue next 4 loads} -> {exp2 epilogue on cur}, so the
// next tile's L1/L2 latency hides under the ~300-cyc epilogue instead of
// serializing (R6's rolled loop stalled on vmcnt(0) each subtile).
// Grid 512 = 2 blocks/CU: all blocks resident, single uniform round.
// S^T via mfma(A=Fj, B=Fi): i = lane&15 (lane-local), j = (lane>>4)*4 + r.
// Self-pair included; final kernel subtracts it exactly.
__global__ __launch_bounds__(256, 3)
void supcon_main(const _Float16* __restrict__ fh, const int* __restrict__ labm,
                 float* __restrict__ Epart, float* __restrict__ Ppart,
                 int M, int jchunk)
{
    const int lane = threadIdx.x & 63;
    const int w = threadIdx.x >> 6;
    const int ibase = blockIdx.x * 256 + w * 64;
    const int rowsel = lane & 15;
    const int grp = lane >> 4;
    const int ksel = grp * 8;      // f16 k-offset within a 32-wide K step

    // register-resident Fi fragments: 4 subtiles x 4 K-steps = 64 regs
    f16x8 bfr[4][4];
    #pragma unroll
    for (int t = 0; t < 4; ++t)
        #pragma unroll
        for (int kk = 0; kk < 4; ++kk)
            bfr[t][kk] = *reinterpret_cast<const f16x8*>(
                &fh[(size_t)(ibase + t * 16 + rowsel) * DD + kk * 32 + ksel]);

    int li[4];
    #pragma unroll
    for (int t = 0; t < 4; ++t) li[t] = labm[ibase + t * 16 + rowsel];

    float esum[4] = {0.f, 0.f, 0.f, 0.f};
    float psum[4] = {0.f, 0.f, 0.f, 0.f};

    const int j0 = blockIdx.y * jchunk;
    const _Float16* aptr = fh + (size_t)(j0 + rowsel) * DD + ksel;
    const int* lptr = labm + j0 + grp * 4;
    const int nsub = jchunk >> 4;      // 32 subtiles (even)

#define LOADT(A, L, s) { \
    _Pragma("unroll") for (int kk = 0; kk < 4; ++kk) \
        A[kk] = *reinterpret_cast<const f16x8*>(aptr + (size_t)(s) * 16 * DD + kk * 32); \
    L = *reinterpret_cast<const int4*>(lptr + (s) * 16); }

#define MFMA16(A, c0, c1, c2, c3) { \
    _Pragma("unroll") for (int kk = 0; kk < 4; ++kk) { \
        c0 = __builtin_amdgcn_mfma_f32_16x16x32_f16(A[kk], bfr[0][kk], c0, 0, 0, 0); \
        c1 = __builtin_amdgcn_mfma_f32_16x16x32_f16(A[kk], bfr[1][kk], c1, 0, 0, 0); \
        c2 = __builtin_amdgcn_mfma_f32_16x16x32_f16(A[kk], bfr[2][kk], c2, 0, 0, 0); \
        c3 = __builtin_amdgcn_mfma_f32_16x16x32_f16(A[kk], bfr[3][kk], c3, 0, 0, 0); } }

#define EPI1(t, cc, L) { \
    float e0 = exp2f(__builtin_fmaf(cc[0], L2E_T, -L2E_T)); \
    float e1 = exp2f(__builtin_fmaf(cc[1], L2E_T, -L2E_T)); \
    float e2 = exp2f(__builtin_fmaf(cc[2], L2E_T, -L2E_T)); \
    float e3 = exp2f(__builtin_fmaf(cc[3], L2E_T, -L2E_T)); \
    esum[t] += (e0 + e1) + (e2 + e3); \
    float p0 = (L.x == li[t]) ? cc[0] : 0.f; \
    float p1 = (L.y == li[t]) ? cc[1] : 0.f; \
    float p2 = (L.z == li[t]) ? cc[2] : 0.f; \
    float p3 = (L.w == li[t]) ? cc[3] : 0.f; \
    psum[t] += (p0 + p1) + (p2 + p3); }

#define EPI4(c0, c1, c2, c3, L) { \
    EPI1(0, c0, L); EPI1(1, c1, L); EPI1(2, c2, L); EPI1(3, c3, L); }

    f16x8 af0[4], af1[4];
    int4 lj0, lj1;
    LOADT(af0, lj0, 0);

    for (int s = 0; s < nsub; s += 2) {
        {   // subtile s (af0); prefetch s+1 between MFMA and epilogue
            f32x4 c0 = {0,0,0,0}, c1 = {0,0,0,0}, c2 = {0,0,0,0}, c3 = {0,0,0,0};
            MFMA16(af0, c0, c1, c2, c3);
            LOADT(af1, lj1, s + 1);          // nsub even: s+1 always valid
            EPI4(c0, c1, c2, c3, lj0);
        }
        {   // subtile s+1 (af1); prefetch s+2
            f32x4 c0 = {0,0,0,0}, c1 = {0,0,0,0}, c2 = {0,0,0,0}, c3 = {0,0,0,0};
            MFMA16(af1, c0, c1, c2, c3);
            if (s + 2 < nsub) LOADT(af0, lj0, s + 2);
            EPI4(c0, c1, c2, c3, lj1);
        }
    }
#undef LOADT
#undef MFMA16
#undef EPI1
#undef EPI4

    // fold lane groups (bits 4,5 = different j rows of the same i)
    #pragma unroll
    for (int t = 0; t < 4; ++t) {
        float e = esum[t], p = psum[t];
        e += __shfl_xor(e, 16); e += __shfl_xor(e, 32);
        p += __shfl_xor(p, 16); p += __shfl_xor(p, 32);
        if (lane < 16) {
            size_t o = (size_t)blockIdx.y * M + ibase + t * 16 + lane;
            Epart[o] = e;
            Ppart[o] = p;
        }
    }
}

// ---- per-row loss term (exact self-term subtraction) + global reduce ----
__global__ __launch_bounds__(256)
void final_fused(const _Float16* __restrict__ fh, const float* __restrict__ Epart,
                 const float* __restrict__ Ppart, const int* __restrict__ labm,
                 const int* __restrict__ hist, float* __restrict__ out, int M)
{
    __shared__ float red[4];
    int i = (blockIdx.x * 256 + threadIdx.x) >> 6;   // wave per row
    int lane = threadIdx.x & 63;
    f16x2 h = *reinterpret_cast<const f16x2*>(&fh[(size_t)i * DD + lane * 2]);
    float x0 = (float)h[0], x1 = (float)h[1];
    float aii = x0 * x0 + x1 * x1;                   // f16 self-dot in fp32
    #pragma unroll
    for (int m = 1; m < 64; m <<= 1) aii += __shfl_xor(aii, m);
    float ep = 0.f;
    if (lane < NSPLIT) ep = Epart[(size_t)lane * M + i];
    else if (lane >= 32 && lane < 32 + NSPLIT) ep = Ppart[(size_t)(lane - 32) * M + i];
    #pragma unroll
    for (int m = 1; m < 32; m <<= 1) ep += __shfl_xor(ep, m);  // within 32-halves
    float P = __shfl(ep, 32);
    float term = 0.f;
    if (lane == 0) {
        int lb = labm[i];
        float cnt = (float)(hist[lb] - 1);
        float E = ep - exp2f(__builtin_fmaf(aii, L2E_T, -L2E_T)); // drop self exp
        float Pc = SHIFT * (P - aii);                              // drop self dot
        term = (SHIFT + logf(E)) - Pc / cnt;
    }
    int wv = threadIdx.x >> 6;
    if (lane == 0) red[wv] = term;
    __syncthreads();
    if (threadIdx.x == 0)
        atomicAdd(out, (red[0] + red[1] + red[2] + red[3]) / (float)M);
}

extern "C" void kernel_launch(void* const* d_in, const int* in_sizes, int n_in,
                              void* d_out, int out_size, void* d_ws, size_t ws_size,
                              hipStream_t stream)
{
    const float* feats = (const float*)d_in[0];
    const int* labels = (const int*)d_in[1];
    const int Bn = in_sizes[1];
    const int M = in_sizes[0] / DD;    // 8192
    const int nrep = M / Bn;           // 2

    char* ws = (char*)d_ws;
    _Float16* fh = (_Float16*)ws;
    size_t off = (size_t)M * DD * sizeof(_Float16);
    int* labm = (int*)(ws + off); off += (size_t)M * sizeof(int);
    int* hist = (int*)(ws + off); off += (size_t)NBINS * sizeof(int);
    off = (off + 255) & ~(size_t)255;
    float* Epart = (float*)(ws + off); off += (size_t)NSPLIT * M * sizeof(float);
    float* Ppart = (float*)(ws + off); off += (size_t)NSPLIT * M * sizeof(float);

    hipMemsetAsync(hist, 0, NBINS * sizeof(int), stream);
    hipMemsetAsync(d_out, 0, sizeof(float), stream);

    norm_kernel<<<M / 4, 256, 0, stream>>>(feats, labels, fh, labm, hist, M, nrep);

    const int jchunk = M / NSPLIT;     // 512 -> 32 subtiles per wave
    dim3 grid(M / 256, NSPLIT);        // 32 x 16 = 512 blocks (2 per CU, 1 round)
    supcon_main<<<grid, 256, 0, stream>>>(fh, labm, Epart, Ppart, M, jchunk);

    final_fused<<<M / 4, 256, 0, stream>>>(fh, Epart, Ppart, labm, hist, (float*)d_out, M);
}